// Round 10
// baseline (268.197 us; speedup 1.0000x reference)
//
#include <hip/hip_runtime.h>
#include <stdint.h>

#define N_VOX   (1 << 19)
#define CIN     64
#define COUT    128
#define BIN_SHIFT 3
#define BINS    (1 << 20)          // (4*8*512*512) >> 3, lambda = 0.5/bin
#define OFF_BITS 4                 // intra-bin arrival offset
#define BPB     256                // bins per k_mega block (~128 positions)
#define NTILES  1024               // scan tiles (1024 bins each)
#define PCAP    512                // max positions per mega block (Poisson(128))
#define EPSV    1e-5f

typedef float f32x4 __attribute__((ext_vector_type(4)));

static __device__ __forceinline__ void nt_store4(float* p, f32x4 v) {
    __builtin_nontemporal_store(v, (f32x4*)p);
}

// MEASUREMENT ROUND: k_mega repeats Phase B+C twice (idempotent rewrites of
// identical values) to lift it above the ~157us poison fills into the top-5
// profile window and expose its counters. dur_us - 170.6 ~= T(PhaseB+C).

#define CLR_INTS (BINS + 4 + 2 * NTILES)

__global__ void k_clear(int* __restrict__ p) {
    int t = blockIdx.x * 256 + threadIdx.x;
    if (t * 4 < CLR_INTS) *(int4*)&p[t * 4] = make_int4(0, 0, 0, 0);
}

__global__ void k_hist(const int* __restrict__ idx, unsigned* __restrict__ packed,
                       int* __restrict__ hist) {
    int j = blockIdx.x * 256 + threadIdx.x;
    int4 v = *(const int4*)&idx[j * 4];
    int lin = ((v.x * 8 + v.y) * 512 + v.z) * 512 + v.w;
    int off = atomicAdd(&hist[lin >> BIN_SHIFT], 1);
    packed[j] = ((unsigned)lin << OFF_BITS) | (unsigned)off;
}

// single-kernel exclusive scan, decoupled lookback, ticket-ordered tiles.
__global__ __launch_bounds__(256) void k_scan(
    const int* __restrict__ hist, int* __restrict__ cursor,
    unsigned long long* __restrict__ tiles, int* __restrict__ ticket) {
    __shared__ int stile;
    __shared__ int wsums[4];
    __shared__ int sprefix;
    int tid = threadIdx.x;
    if (tid == 0) stile = atomicAdd(ticket, 1);
    __syncthreads();
    int tile = stile;
    int base = tile * 1024 + tid * 4;
    int4 v = *(const int4*)&hist[base];
    int t3 = v.x + v.y + v.z + v.w;
    int lane = tid & 63, w = tid >> 6;
    int incl = t3;
    #pragma unroll
    for (int off = 1; off < 64; off <<= 1) {
        int u = __shfl_up(incl, off);
        if (lane >= off) incl += u;
    }
    if (lane == 63) wsums[w] = incl;
    __syncthreads();
    int woff = (w > 0 ? wsums[0] : 0) + (w > 1 ? wsums[1] : 0) + (w > 2 ? wsums[2] : 0);
    int total = wsums[0] + wsums[1] + wsums[2] + wsums[3];
    int texcl = woff + incl - t3;
    if (tid == 0) {
        unsigned long long st = (tile == 0) ? 2ull : 1ull;
        atomicExch(&tiles[tile], (st << 40) | (unsigned long long)(unsigned)total);
        int pfx = 0;
        if (tile > 0) {
            int p = tile - 1;
            while (true) {
                unsigned long long d = atomicAdd(&tiles[p], 0ull);
                unsigned long long st2 = d >> 40;
                if (st2 == 0) { __builtin_amdgcn_s_sleep(2); continue; }
                pfx += (int)(unsigned)(d & 0xFFFFFFFFull);
                if (st2 == 2ull) break;
                p--;
            }
            atomicExch(&tiles[tile],
                       (2ull << 40) | (unsigned long long)(unsigned)(pfx + total));
        }
        sprefix = pfx;
    }
    __syncthreads();
    int prefix = sprefix + texcl;
    int4 e;
    e.x = prefix;
    e.y = prefix + v.x;
    e.z = prefix + v.x + v.y;
    e.w = prefix + v.x + v.y + v.z;
    *(int4*)&cursor[base] = e;
}

__global__ void k_scatter(const unsigned* __restrict__ packed, const int* __restrict__ cursor,
                          int* __restrict__ perm) {
    int j = blockIdx.x * 256 + threadIdx.x;
    unsigned p = packed[j];
    int pos = cursor[p >> (OFF_BITS + BIN_SHIFT)] + (int)(p & ((1u << OFF_BITS) - 1u));
    perm[pos] = j;
}

__global__ __launch_bounds__(256) void k_mega(
    const float* __restrict__ feats, const float* __restrict__ weight,
    const float* __restrict__ gamma, const float* __restrict__ beta,
    const int* __restrict__ hist, const int* __restrict__ cursor,
    const unsigned* __restrict__ packed, int* __restrict__ perm,
    float* __restrict__ out) {
    __shared__ float featb[4][8][CIN];
    __shared__ unsigned slin[PCAP];
    __shared__ int sperm[PCAP];
    __shared__ unsigned short vpos[PCAP];
    __shared__ unsigned ibit[PCAP / 32];
    __shared__ int wsum[4];

    int tid = threadIdx.x;
    int w = tid >> 6, lane = tid & 63;
    int B0 = blockIdx.x * BPB;
    int p0 = cursor[B0];
    int p1 = (B0 + BPB < BINS) ? cursor[B0 + BPB] : N_VOX;
    int npos = p1 - p0;

    if (tid < PCAP / 32) ibit[tid] = 0;

    // Phase A: per-bin stable fixup; cache lin/perm in LDS
    int b = B0 + tid;
    int c = hist[b];
    int s = cursor[b];
    if (c >= 2) {
        for (int i = 1; i < c; i++) {
            int pj = perm[s + i];
            unsigned long long kj =
                ((unsigned long long)(packed[pj] >> OFF_BITS) << 19) | (unsigned)pj;
            int m = i - 1;
            while (m >= 0) {
                int pm = perm[s + m];
                unsigned long long km =
                    ((unsigned long long)(packed[pm] >> OFF_BITS) << 19) | (unsigned)pm;
                if (km <= kj) break;
                perm[s + m + 1] = pm;
                m--;
            }
            perm[s + m + 1] = pj;
        }
    }
    int myv = 0;
    for (int i = 0; i < c; i++) {
        int lp = s - p0 + i;
        int j = perm[s + i];
        unsigned lin = packed[j] >> OFF_BITS;
        slin[lp] = lin;
        sperm[lp] = j;
        myv += ((lin & 0x201u) == 0u) ? 1 : 0;
    }
    int incl = myv;
    #pragma unroll
    for (int off = 1; off < 64; off <<= 1) {
        int u = __shfl_up(incl, off);
        if (lane >= off) incl += u;
    }
    if (lane == 63) wsum[w] = incl;
    __syncthreads();
    int s0 = wsum[0], s1 = wsum[1], s2 = wsum[2], s3 = wsum[3];
    int nv = s0 + s1 + s2 + s3;
    int woff = (w > 0 ? s0 : 0) + (w > 1 ? s1 : 0) + (w > 2 ? s2 : 0);
    int basev = woff + incl - myv;
    for (int i = 0; i < c; i++) {
        int lp = s - p0 + i;
        if ((slin[lp] & 0x201u) == 0u) vpos[basev++] = (unsigned short)lp;
        else atomicOr(&ibit[lp >> 5], 1u << (lp & 31));
    }
    __syncthreads();

    int half = lane >> 5, l32 = lane & 31;

    for (int rep = 0; rep < 2; ++rep) {   // MEASUREMENT: B+C twice, idempotent
        // Phase B
        {
            f32x4 mi = {-1.f, -1.f, -1.f, -1.f};
            for (int lp = tid; lp < npos; lp += 256) {
                if ((ibit[lp >> 5] >> (lp & 31)) & 1u)
                    nt_store4(&out[(size_t)N_VOX * COUT + (size_t)(p0 + lp) * 4], mi);
            }
            f32x4 z = {0.f, 0.f, 0.f, 0.f};
            for (int lp = w * 2 + half; lp < npos; lp += 8) {
                if ((ibit[lp >> 5] >> (lp & 31)) & 1u)
                    nt_store4(&out[(size_t)(p0 + lp) * COUT + l32 * 4], z);
            }
        }

        // Phase C
        if (nv == 0) continue;
        const f32x4* Wg4 = (const f32x4*)weight;
        f32x4 gv = *(const f32x4*)&gamma[l32 * 4];
        f32x4 bv = *(const f32x4*)&beta[l32 * 4];

        for (int m0 = 0; m0 < nv; m0 += 32) {
            int mb = m0 + w * 8;
            if (mb >= nv) continue;
            #pragma unroll
            for (int i = 0; i < 8; i++) {
                int m = mb + i;
                int lp = vpos[(m < nv) ? m : 0];
                featb[w][i][lane] = feats[(size_t)sperm[lp] * CIN + lane];
            }

            f32x4 acc[4];
            #pragma unroll
            for (int i = 0; i < 4; i++) acc[i] = (f32x4){0.f, 0.f, 0.f, 0.f};

            #pragma unroll 4
            for (int k0 = 0; k0 < CIN; k0 += 4) {
                f32x4 wv0 = Wg4[(k0 + 0) * 32 + l32];
                f32x4 wv1 = Wg4[(k0 + 1) * 32 + l32];
                f32x4 wv2 = Wg4[(k0 + 2) * 32 + l32];
                f32x4 wv3 = Wg4[(k0 + 3) * 32 + l32];
                #pragma unroll
                for (int ii = 0; ii < 4; ii++) {
                    float4 f = *(float4*)&featb[w][2 * ii + half][k0];
                    acc[ii] += f.x * wv0;
                    acc[ii] += f.y * wv1;
                    acc[ii] += f.z * wv2;
                    acc[ii] += f.w * wv3;
                }
            }

            #pragma unroll
            for (int ii = 0; ii < 4; ii++) {
                int m = mb + 2 * ii + half;
                f32x4 a = acc[ii];
                float sm = a.x + a.y + a.z + a.w;
                float sq = a.x * a.x + a.y * a.y + a.z * a.z + a.w * a.w;
                #pragma unroll
                for (int off = 16; off > 0; off >>= 1) {
                    sm += __shfl_xor(sm, off);
                    sq += __shfl_xor(sq, off);
                }
                float mean = sm * (1.0f / COUT);
                float var  = fmaxf(sq * (1.0f / COUT) - mean * mean, 0.0f);
                float rstd = rsqrtf(var + EPSV);
                if (m < nv) {
                    int lp = vpos[m];
                    int pos = p0 + lp;
                    f32x4 o = (a - mean) * rstd * gv + bv;
                    nt_store4(&out[(size_t)pos * COUT + l32 * 4], o);
                    if (l32 == 0) {
                        unsigned lin = slin[lp];
                        f32x4 ni;
                        ni.x = (float)(lin >> 21);
                        ni.y = (float)((lin >> 18) & 7u);
                        ni.z = (float)(((lin >> 9) & 511u) >> 1);
                        ni.w = (float)((lin & 511u) >> 1);
                        nt_store4(&out[(size_t)N_VOX * COUT + (size_t)pos * 4], ni);
                    }
                }
            }
        }
    }
}

extern "C" void kernel_launch(void* const* d_in, const int* in_sizes, int n_in,
                              void* d_out, int out_size, void* d_ws, size_t ws_size,
                              hipStream_t stream) {
    const float* feats  = (const float*)d_in[0];
    const int*   idx    = (const int*)d_in[1];
    const float* weight = (const float*)d_in[2];
    const float* gamma  = (const float*)d_in[3];
    const float* beta   = (const float*)d_in[4];
    float* out = (float*)d_out;

    int* ws = (int*)d_ws;
    int*                hist   = ws;                         // BINS
    int*                ticket = ws + BINS;                  // 1 (+3 pad)
    unsigned long long* tiles  = (unsigned long long*)(ws + BINS + 4);  // NTILES
    int*                cursor = ws + BINS + 4 + 2 * NTILES; // BINS
    unsigned*           packed = (unsigned*)(cursor + BINS); // N
    int*                perm   = (int*)(packed + N_VOX);     // N

    k_clear<<<(CLR_INTS / 4 + 255) / 256, 256, 0, stream>>>(ws);
    k_hist<<<N_VOX / 256, 256, 0, stream>>>(idx, packed, hist);
    k_scan<<<NTILES, 256, 0, stream>>>(hist, cursor, tiles, ticket);
    k_scatter<<<N_VOX / 256, 256, 0, stream>>>(packed, cursor, perm);
    k_mega<<<BINS / BPB, 256, 0, stream>>>(feats, weight, gamma, beta,
                                           hist, cursor, packed, perm, out);
}

// Round 11
// 196.859 us; speedup vs baseline: 1.3624x; 1.3624x over previous
//
#include <hip/hip_runtime.h>
#include <stdint.h>

#define N_VOX   (1 << 19)
#define CIN     64
#define COUT    128
#define BIN_SHIFT 3
#define BINS    (1 << 20)          // (4*8*512*512) >> 3, lambda = 0.5/bin
#define OFF_BITS 4                 // intra-bin arrival offset
#define BPB     256                // bins per k_mega block (~128 positions)
#define NTILES  1024               // scan tiles (1024 bins each)
#define PCAP    512                // max positions per mega block (Poisson(128))
#define EPSV    1e-5f

typedef float f32x4 __attribute__((ext_vector_type(4)));

static __device__ __forceinline__ void nt_store4(float* p, f32x4 v) {
    __builtin_nontemporal_store(v, (f32x4*)p);
}

// Round-10 measurement: PhaseB+C = 97.6us @2.5TB/s (store-bound), PhaseA = 41us
// (scattered perm/packed gathers). Fixes: (1) scatter writes (lin,j) records ->
// k_mega Phase A is coalesced + LDS-only fixup; (2) invalid-row zeros/-1 move
// to a pure prefill kernel at fill-rate (~6.9 TB/s measured), Phase C
// overwrites valid rows only.
//
// ws ints: hist[BINS] | ticket(1)+pad(3) | tiles[2*NTILES] | cursor[BINS]
//          | packed[N] | recs[2*N]   (~14.3 MB)

#define CLR_INTS (BINS + 4 + 2 * NTILES)
#define OUT0_4   (N_VOX * COUT / 4)            // float4s in out_f
#define TOT_4    (N_VOX * (COUT + 4) / 4)      // + new_idx region

// prefill: zero out_f, -1 new_idx, clear hist/ticket/tiles. grid-stride.
__global__ __launch_bounds__(256) void k_zero(float* __restrict__ out,
                                              int* __restrict__ ws) {
    int gid = blockIdx.x * 256 + threadIdx.x;
    int stride = gridDim.x * 256;
    f32x4 z  = {0.f, 0.f, 0.f, 0.f};
    f32x4 mi = {-1.f, -1.f, -1.f, -1.f};
    for (int t = gid; t < TOT_4; t += stride)
        nt_store4(&out[(size_t)t * 4], (t < OUT0_4) ? z : mi);
    for (int t = gid; t < CLR_INTS / 4; t += stride)
        *(int4*)&ws[t * 4] = make_int4(0, 0, 0, 0);
}

__global__ void k_hist(const int* __restrict__ idx, unsigned* __restrict__ packed,
                       int* __restrict__ hist) {
    int j = blockIdx.x * 256 + threadIdx.x;
    int4 v = *(const int4*)&idx[j * 4];
    int lin = ((v.x * 8 + v.y) * 512 + v.z) * 512 + v.w;
    int off = atomicAdd(&hist[lin >> BIN_SHIFT], 1);
    packed[j] = ((unsigned)lin << OFF_BITS) | (unsigned)off;
}

// single-kernel exclusive scan, decoupled lookback, ticket-ordered tiles.
__global__ __launch_bounds__(256) void k_scan(
    const int* __restrict__ hist, int* __restrict__ cursor,
    unsigned long long* __restrict__ tiles, int* __restrict__ ticket) {
    __shared__ int stile;
    __shared__ int wsums[4];
    __shared__ int sprefix;
    int tid = threadIdx.x;
    if (tid == 0) stile = atomicAdd(ticket, 1);
    __syncthreads();
    int tile = stile;
    int base = tile * 1024 + tid * 4;
    int4 v = *(const int4*)&hist[base];
    int t3 = v.x + v.y + v.z + v.w;
    int lane = tid & 63, w = tid >> 6;
    int incl = t3;
    #pragma unroll
    for (int off = 1; off < 64; off <<= 1) {
        int u = __shfl_up(incl, off);
        if (lane >= off) incl += u;
    }
    if (lane == 63) wsums[w] = incl;
    __syncthreads();
    int woff = (w > 0 ? wsums[0] : 0) + (w > 1 ? wsums[1] : 0) + (w > 2 ? wsums[2] : 0);
    int total = wsums[0] + wsums[1] + wsums[2] + wsums[3];
    int texcl = woff + incl - t3;
    if (tid == 0) {
        unsigned long long st = (tile == 0) ? 2ull : 1ull;
        atomicExch(&tiles[tile], (st << 40) | (unsigned long long)(unsigned)total);
        int pfx = 0;
        if (tile > 0) {
            int p = tile - 1;
            while (true) {
                unsigned long long d = atomicAdd(&tiles[p], 0ull);
                unsigned long long st2 = d >> 40;
                if (st2 == 0) { __builtin_amdgcn_s_sleep(2); continue; }
                pfx += (int)(unsigned)(d & 0xFFFFFFFFull);
                if (st2 == 2ull) break;
                p--;
            }
            atomicExch(&tiles[tile],
                       (2ull << 40) | (unsigned long long)(unsigned)(pfx + total));
        }
        sprefix = pfx;
    }
    __syncthreads();
    int prefix = sprefix + texcl;
    int4 e;
    e.x = prefix;
    e.y = prefix + v.x;
    e.z = prefix + v.x + v.y;
    e.w = prefix + v.x + v.y + v.z;
    *(int4*)&cursor[base] = e;
}

// writes sorted-position records (lin, origrow): Phase A becomes coalesced.
__global__ void k_scatter(const unsigned* __restrict__ packed, const int* __restrict__ cursor,
                          uint2* __restrict__ recs) {
    int j = blockIdx.x * 256 + threadIdx.x;
    unsigned p = packed[j];
    unsigned lin = p >> OFF_BITS;
    int pos = cursor[lin >> BIN_SHIFT] + (int)(p & ((1u << OFF_BITS) - 1u));
    recs[pos] = make_uint2(lin, (unsigned)j);
}

// ---------- fused fixup + GEMM + LN (valid rows only) ----------
__global__ __launch_bounds__(256) void k_mega(
    const float* __restrict__ feats, const float* __restrict__ weight,
    const float* __restrict__ gamma, const float* __restrict__ beta,
    const int* __restrict__ hist, const int* __restrict__ cursor,
    const uint2* __restrict__ recs, float* __restrict__ out) {
    __shared__ float featb[4][8][CIN];         // 8 KB (wave-private slices)
    __shared__ unsigned slin[PCAP];            // 2 KB
    __shared__ int sperm[PCAP];                // 2 KB
    __shared__ unsigned short vpos[PCAP];      // 1 KB
    __shared__ int wsum[4];

    int tid = threadIdx.x;
    int w = tid >> 6, lane = tid & 63;
    int B0 = blockIdx.x * BPB;
    int p0 = cursor[B0];
    int p1 = (B0 + BPB < BINS) ? cursor[B0 + BPB] : N_VOX;
    int npos = p1 - p0;                        // ~Poisson(128), < PCAP

    // Phase A1: coalesced load of records into LDS
    for (int lp = tid; lp < npos; lp += 256) {
        uint2 r = recs[p0 + lp];
        slin[lp] = r.x;
        sperm[lp] = (int)r.y;
    }
    __syncthreads();

    // Phase A2: per-bin stable fixup in LDS (key = lin<<19 | j) + validity
    int b = B0 + tid;
    int c = hist[b];
    int ls = cursor[b] - p0;
    if (c >= 2) {
        for (int i = 1; i < c; i++) {
            unsigned lj = slin[ls + i];
            int pj = sperm[ls + i];
            unsigned long long kj = ((unsigned long long)lj << 19) | (unsigned)pj;
            int m = i - 1;
            while (m >= 0) {
                unsigned lm = slin[ls + m];
                int pm = sperm[ls + m];
                unsigned long long km = ((unsigned long long)lm << 19) | (unsigned)pm;
                if (km <= kj) break;
                slin[ls + m + 1] = lm;
                sperm[ls + m + 1] = pm;
                m--;
            }
            slin[ls + m + 1] = lj;
            sperm[ls + m + 1] = pj;
        }
    }
    int myv = 0;
    for (int i = 0; i < c; i++)
        myv += ((slin[ls + i] & 0x201u) == 0u) ? 1 : 0;
    // block-exclusive scan of myv (wave shuffle + 1 barrier)
    int incl = myv;
    #pragma unroll
    for (int off = 1; off < 64; off <<= 1) {
        int u = __shfl_up(incl, off);
        if (lane >= off) incl += u;
    }
    if (lane == 63) wsum[w] = incl;
    __syncthreads();
    int s0 = wsum[0], s1 = wsum[1], s2 = wsum[2], s3 = wsum[3];
    int nv = s0 + s1 + s2 + s3;
    int woff = (w > 0 ? s0 : 0) + (w > 1 ? s1 : 0) + (w > 2 ? s2 : 0);
    int basev = woff + incl - myv;
    for (int i = 0; i < c; i++) {
        int lp = ls + i;
        if ((slin[lp] & 0x201u) == 0u) vpos[basev++] = (unsigned short)lp;
    }
    __syncthreads();

    // Phase C: GEMM + LN, 2 rows per wave pass (32-lane halves), f32x4 stores
    if (nv == 0) return;
    int half = lane >> 5, l32 = lane & 31;
    const f32x4* Wg4 = (const f32x4*)weight;   // [64][32] of float4
    f32x4 gv = *(const f32x4*)&gamma[l32 * 4];
    f32x4 bv = *(const f32x4*)&beta[l32 * 4];

    for (int m0 = 0; m0 < nv; m0 += 32) {
        int mb = m0 + w * 8;
        if (mb >= nv) continue;                 // no barriers below: safe
        #pragma unroll
        for (int i = 0; i < 8; i++) {
            int m = mb + i;
            int lp = vpos[(m < nv) ? m : 0];
            featb[w][i][lane] = feats[(size_t)sperm[lp] * CIN + lane];
        }

        f32x4 acc[4];
        #pragma unroll
        for (int i = 0; i < 4; i++) acc[i] = (f32x4){0.f, 0.f, 0.f, 0.f};

        #pragma unroll 4
        for (int k0 = 0; k0 < CIN; k0 += 4) {
            f32x4 wv0 = Wg4[(k0 + 0) * 32 + l32];
            f32x4 wv1 = Wg4[(k0 + 1) * 32 + l32];
            f32x4 wv2 = Wg4[(k0 + 2) * 32 + l32];
            f32x4 wv3 = Wg4[(k0 + 3) * 32 + l32];
            #pragma unroll
            for (int ii = 0; ii < 4; ii++) {
                float4 f = *(float4*)&featb[w][2 * ii + half][k0];
                acc[ii] += f.x * wv0;
                acc[ii] += f.y * wv1;
                acc[ii] += f.z * wv2;
                acc[ii] += f.w * wv3;
            }
        }

        #pragma unroll
        for (int ii = 0; ii < 4; ii++) {
            int m = mb + 2 * ii + half;
            f32x4 a = acc[ii];
            float sm = a.x + a.y + a.z + a.w;
            float sq = a.x * a.x + a.y * a.y + a.z * a.z + a.w * a.w;
            #pragma unroll
            for (int off = 16; off > 0; off >>= 1) {   // reduce within 32-lane half
                sm += __shfl_xor(sm, off);
                sq += __shfl_xor(sq, off);
            }
            float mean = sm * (1.0f / COUT);
            float var  = fmaxf(sq * (1.0f / COUT) - mean * mean, 0.0f);
            float rstd = rsqrtf(var + EPSV);
            if (m < nv) {
                int lp = vpos[m];
                int pos = p0 + lp;
                f32x4 o = (a - mean) * rstd * gv + bv;
                nt_store4(&out[(size_t)pos * COUT + l32 * 4], o);
                if (l32 == 0) {
                    unsigned lin = slin[lp];
                    f32x4 ni;
                    ni.x = (float)(lin >> 21);
                    ni.y = (float)((lin >> 18) & 7u);
                    ni.z = (float)(((lin >> 9) & 511u) >> 1);
                    ni.w = (float)((lin & 511u) >> 1);
                    nt_store4(&out[(size_t)N_VOX * COUT + (size_t)pos * 4], ni);
                }
            }
        }
    }
}

extern "C" void kernel_launch(void* const* d_in, const int* in_sizes, int n_in,
                              void* d_out, int out_size, void* d_ws, size_t ws_size,
                              hipStream_t stream) {
    const float* feats  = (const float*)d_in[0];
    const int*   idx    = (const int*)d_in[1];
    const float* weight = (const float*)d_in[2];
    const float* gamma  = (const float*)d_in[3];
    const float* beta   = (const float*)d_in[4];
    float* out = (float*)d_out;

    int* ws = (int*)d_ws;
    int*                hist   = ws;                         // BINS
    int*                ticket = ws + BINS;                  // 1 (+3 pad)
    unsigned long long* tiles  = (unsigned long long*)(ws + BINS + 4);  // NTILES
    int*                cursor = ws + BINS + 4 + 2 * NTILES; // BINS
    unsigned*           packed = (unsigned*)(cursor + BINS); // N
    uint2*              recs   = (uint2*)(packed + N_VOX);   // N x 8B

    k_zero<<<2048, 256, 0, stream>>>(out, ws);
    k_hist<<<N_VOX / 256, 256, 0, stream>>>(idx, packed, hist);
    k_scan<<<NTILES, 256, 0, stream>>>(hist, cursor, tiles, ticket);
    k_scatter<<<N_VOX / 256, 256, 0, stream>>>(packed, cursor, recs);
    k_mega<<<BINS / BPB, 256, 0, stream>>>(feats, weight, gamma, beta,
                                           hist, cursor, recs, out);
}

// Round 12
// 190.240 us; speedup vs baseline: 1.4098x; 1.0348x over previous
//
#include <hip/hip_runtime.h>
#include <stdint.h>

#define N_VOX   (1 << 19)
#define CIN     64
#define COUT    128
#define BIN_SHIFT 3
#define BINS    (1 << 20)          // (4*8*512*512) >> 3, lambda = 0.5/bin
#define OFF_BITS 4                 // intra-bin arrival offset
#define BPB     256                // bins per k_mega block (~128 positions)
#define NTILES  1024               // scan tiles (1024 bins each)
#define PCAP    512                // max positions per mega block (Poisson(128))
#define EPSV    1e-5f

typedef float f32x4 __attribute__((ext_vector_type(4)));

static __device__ __forceinline__ void nt_store4(float* p, f32x4 v) {
    __builtin_nontemporal_store(v, (f32x4*)p);
}

// Store model (fitted r4-r11): plain DENSE monotone stores ~6.9 TB/s (L2
// write-back); nontemporal stores ~2.6-2.8 TB/s (L2 bypass); plain
// CONDITIONAL/hole-y stores ~1.1 TB/s. => prefill = plain dense; scattered
// valid-row writes in k_mega = nt.
//
// ws ints: hist[BINS] | ticket(1)+pad(3) | tiles[2*NTILES] | cursor[BINS]
//          | packed[N] | recs[2*N]

#define CLR_INTS (BINS + 4 + 2 * NTILES)
#define OUT0_4   (N_VOX * COUT / 4)            // float4s in out_f
#define IDX_4    (N_VOX)                       // float4s in new_idx ( [N,4] )

// prefill: PLAIN dense stores. Loop 1: zeros over out_f. Loop 2: -1 over
// new_idx. Loop 3: clear ws metadata. Branch-free monotone sweeps.
__global__ __launch_bounds__(256) void k_zero(float* __restrict__ out,
                                              int* __restrict__ ws) {
    int gid = blockIdx.x * 256 + threadIdx.x;
    int stride = gridDim.x * 256;
    float4 z  = make_float4(0.f, 0.f, 0.f, 0.f);
    float4 mi = make_float4(-1.f, -1.f, -1.f, -1.f);
    for (int t = gid; t < OUT0_4; t += stride)
        *(float4*)&out[(size_t)t * 4] = z;
    float* oidx = out + (size_t)N_VOX * COUT;
    for (int t = gid; t < IDX_4; t += stride)
        *(float4*)&oidx[(size_t)t * 4] = mi;
    for (int t = gid; t < CLR_INTS / 4; t += stride)
        *(int4*)&ws[t * 4] = make_int4(0, 0, 0, 0);
}

__global__ void k_hist(const int* __restrict__ idx, unsigned* __restrict__ packed,
                       int* __restrict__ hist) {
    int j = blockIdx.x * 256 + threadIdx.x;
    int4 v = *(const int4*)&idx[j * 4];
    int lin = ((v.x * 8 + v.y) * 512 + v.z) * 512 + v.w;
    int off = atomicAdd(&hist[lin >> BIN_SHIFT], 1);
    packed[j] = ((unsigned)lin << OFF_BITS) | (unsigned)off;
}

// single-kernel exclusive scan, decoupled lookback, ticket-ordered tiles.
__global__ __launch_bounds__(256) void k_scan(
    const int* __restrict__ hist, int* __restrict__ cursor,
    unsigned long long* __restrict__ tiles, int* __restrict__ ticket) {
    __shared__ int stile;
    __shared__ int wsums[4];
    __shared__ int sprefix;
    int tid = threadIdx.x;
    if (tid == 0) stile = atomicAdd(ticket, 1);
    __syncthreads();
    int tile = stile;
    int base = tile * 1024 + tid * 4;
    int4 v = *(const int4*)&hist[base];
    int t3 = v.x + v.y + v.z + v.w;
    int lane = tid & 63, w = tid >> 6;
    int incl = t3;
    #pragma unroll
    for (int off = 1; off < 64; off <<= 1) {
        int u = __shfl_up(incl, off);
        if (lane >= off) incl += u;
    }
    if (lane == 63) wsums[w] = incl;
    __syncthreads();
    int woff = (w > 0 ? wsums[0] : 0) + (w > 1 ? wsums[1] : 0) + (w > 2 ? wsums[2] : 0);
    int total = wsums[0] + wsums[1] + wsums[2] + wsums[3];
    int texcl = woff + incl - t3;
    if (tid == 0) {
        unsigned long long st = (tile == 0) ? 2ull : 1ull;
        atomicExch(&tiles[tile], (st << 40) | (unsigned long long)(unsigned)total);
        int pfx = 0;
        if (tile > 0) {
            int p = tile - 1;
            while (true) {
                unsigned long long d = atomicAdd(&tiles[p], 0ull);
                unsigned long long st2 = d >> 40;
                if (st2 == 0) { __builtin_amdgcn_s_sleep(2); continue; }
                pfx += (int)(unsigned)(d & 0xFFFFFFFFull);
                if (st2 == 2ull) break;
                p--;
            }
            atomicExch(&tiles[tile],
                       (2ull << 40) | (unsigned long long)(unsigned)(pfx + total));
        }
        sprefix = pfx;
    }
    __syncthreads();
    int prefix = sprefix + texcl;
    int4 e;
    e.x = prefix;
    e.y = prefix + v.x;
    e.z = prefix + v.x + v.y;
    e.w = prefix + v.x + v.y + v.z;
    *(int4*)&cursor[base] = e;
}

// writes sorted-position records (lin, origrow): k_mega Phase A is coalesced.
__global__ void k_scatter(const unsigned* __restrict__ packed, const int* __restrict__ cursor,
                          uint2* __restrict__ recs) {
    int j = blockIdx.x * 256 + threadIdx.x;
    unsigned p = packed[j];
    unsigned lin = p >> OFF_BITS;
    int pos = cursor[lin >> BIN_SHIFT] + (int)(p & ((1u << OFF_BITS) - 1u));
    recs[pos] = make_uint2(lin, (unsigned)j);
}

// ---------- fused fixup + GEMM + LN (valid rows only) ----------
__global__ __launch_bounds__(256) void k_mega(
    const float* __restrict__ feats, const float* __restrict__ weight,
    const float* __restrict__ gamma, const float* __restrict__ beta,
    const int* __restrict__ hist, const int* __restrict__ cursor,
    const uint2* __restrict__ recs, float* __restrict__ out) {
    __shared__ float featb[4][8][CIN];         // 8 KB (wave-private slices)
    __shared__ unsigned slin[PCAP];            // 2 KB
    __shared__ int sperm[PCAP];                // 2 KB
    __shared__ unsigned short vpos[PCAP];      // 1 KB
    __shared__ int wsum[4];

    int tid = threadIdx.x;
    int w = tid >> 6, lane = tid & 63;
    int B0 = blockIdx.x * BPB;
    int p0 = cursor[B0];
    int p1 = (B0 + BPB < BINS) ? cursor[B0 + BPB] : N_VOX;
    int npos = p1 - p0;                        // ~Poisson(128), < PCAP

    // Phase A1: coalesced load of records into LDS
    for (int lp = tid; lp < npos; lp += 256) {
        uint2 r = recs[p0 + lp];
        slin[lp] = r.x;
        sperm[lp] = (int)r.y;
    }
    __syncthreads();

    // Phase A2: per-bin stable fixup in LDS (key = lin<<19 | j) + validity
    int b = B0 + tid;
    int c = hist[b];
    int ls = cursor[b] - p0;
    if (c >= 2) {
        for (int i = 1; i < c; i++) {
            unsigned lj = slin[ls + i];
            int pj = sperm[ls + i];
            unsigned long long kj = ((unsigned long long)lj << 19) | (unsigned)pj;
            int m = i - 1;
            while (m >= 0) {
                unsigned lm = slin[ls + m];
                int pm = sperm[ls + m];
                unsigned long long km = ((unsigned long long)lm << 19) | (unsigned)pm;
                if (km <= kj) break;
                slin[ls + m + 1] = lm;
                sperm[ls + m + 1] = pm;
                m--;
            }
            slin[ls + m + 1] = lj;
            sperm[ls + m + 1] = pj;
        }
    }
    int myv = 0;
    for (int i = 0; i < c; i++)
        myv += ((slin[ls + i] & 0x201u) == 0u) ? 1 : 0;
    int incl = myv;
    #pragma unroll
    for (int off = 1; off < 64; off <<= 1) {
        int u = __shfl_up(incl, off);
        if (lane >= off) incl += u;
    }
    if (lane == 63) wsum[w] = incl;
    __syncthreads();
    int s0 = wsum[0], s1 = wsum[1], s2 = wsum[2], s3 = wsum[3];
    int nv = s0 + s1 + s2 + s3;
    int woff = (w > 0 ? s0 : 0) + (w > 1 ? s1 : 0) + (w > 2 ? s2 : 0);
    int basev = woff + incl - myv;
    for (int i = 0; i < c; i++) {
        int lp = ls + i;
        if ((slin[lp] & 0x201u) == 0u) vpos[basev++] = (unsigned short)lp;
    }
    __syncthreads();

    // Phase C: GEMM + LN, 2 rows per wave pass (32-lane halves), f32x4 nt stores
    if (nv == 0) return;
    int half = lane >> 5, l32 = lane & 31;
    const f32x4* Wg4 = (const f32x4*)weight;   // [64][32] of float4
    f32x4 gv = *(const f32x4*)&gamma[l32 * 4];
    f32x4 bv = *(const f32x4*)&beta[l32 * 4];

    for (int m0 = 0; m0 < nv; m0 += 32) {
        int mb = m0 + w * 8;
        if (mb >= nv) continue;                 // no barriers below: safe
        #pragma unroll
        for (int i = 0; i < 8; i++) {
            int m = mb + i;
            int lp = vpos[(m < nv) ? m : 0];
            featb[w][i][lane] = feats[(size_t)sperm[lp] * CIN + lane];
        }

        f32x4 acc[4];
        #pragma unroll
        for (int i = 0; i < 4; i++) acc[i] = (f32x4){0.f, 0.f, 0.f, 0.f};

        #pragma unroll 4
        for (int k0 = 0; k0 < CIN; k0 += 4) {
            f32x4 wv0 = Wg4[(k0 + 0) * 32 + l32];
            f32x4 wv1 = Wg4[(k0 + 1) * 32 + l32];
            f32x4 wv2 = Wg4[(k0 + 2) * 32 + l32];
            f32x4 wv3 = Wg4[(k0 + 3) * 32 + l32];
            #pragma unroll
            for (int ii = 0; ii < 4; ii++) {
                float4 f = *(float4*)&featb[w][2 * ii + half][k0];
                acc[ii] += f.x * wv0;
                acc[ii] += f.y * wv1;
                acc[ii] += f.z * wv2;
                acc[ii] += f.w * wv3;
            }
        }

        #pragma unroll
        for (int ii = 0; ii < 4; ii++) {
            int m = mb + 2 * ii + half;
            f32x4 a = acc[ii];
            float sm = a.x + a.y + a.z + a.w;
            float sq = a.x * a.x + a.y * a.y + a.z * a.z + a.w * a.w;
            #pragma unroll
            for (int off = 16; off > 0; off >>= 1) {   // reduce within 32-lane half
                sm += __shfl_xor(sm, off);
                sq += __shfl_xor(sq, off);
            }
            float mean = sm * (1.0f / COUT);
            float var  = fmaxf(sq * (1.0f / COUT) - mean * mean, 0.0f);
            float rstd = rsqrtf(var + EPSV);
            if (m < nv) {
                int lp = vpos[m];
                int pos = p0 + lp;
                f32x4 o = (a - mean) * rstd * gv + bv;
                nt_store4(&out[(size_t)pos * COUT + l32 * 4], o);
                if (l32 == 0) {
                    unsigned lin = slin[lp];
                    f32x4 ni;
                    ni.x = (float)(lin >> 21);
                    ni.y = (float)((lin >> 18) & 7u);
                    ni.z = (float)(((lin >> 9) & 511u) >> 1);
                    ni.w = (float)((lin & 511u) >> 1);
                    nt_store4(&out[(size_t)N_VOX * COUT + (size_t)pos * 4], ni);
                }
            }
        }
    }
}

extern "C" void kernel_launch(void* const* d_in, const int* in_sizes, int n_in,
                              void* d_out, int out_size, void* d_ws, size_t ws_size,
                              hipStream_t stream) {
    const float* feats  = (const float*)d_in[0];
    const int*   idx    = (const int*)d_in[1];
    const float* weight = (const float*)d_in[2];
    const float* gamma  = (const float*)d_in[3];
    const float* beta   = (const float*)d_in[4];
    float* out = (float*)d_out;

    int* ws = (int*)d_ws;
    int*                hist   = ws;                         // BINS
    int*                ticket = ws + BINS;                  // 1 (+3 pad)
    unsigned long long* tiles  = (unsigned long long*)(ws + BINS + 4);  // NTILES
    int*                cursor = ws + BINS + 4 + 2 * NTILES; // BINS
    unsigned*           packed = (unsigned*)(cursor + BINS); // N
    uint2*              recs   = (uint2*)(packed + N_VOX);   // N x 8B

    k_zero<<<4096, 256, 0, stream>>>(out, ws);
    k_hist<<<N_VOX / 256, 256, 0, stream>>>(idx, packed, hist);
    k_scan<<<NTILES, 256, 0, stream>>>(hist, cursor, tiles, ticket);
    k_scatter<<<N_VOX / 256, 256, 0, stream>>>(packed, cursor, recs);
    k_mega<<<BINS / BPB, 256, 0, stream>>>(feats, weight, gamma, beta,
                                           hist, cursor, recs, out);
}

// Round 13
// 182.295 us; speedup vs baseline: 1.4712x; 1.0436x over previous
//
#include <hip/hip_runtime.h>
#include <stdint.h>

#define N_VOX   (1 << 19)
#define CIN     64
#define COUT    128
#define BIN_SHIFT 3
#define BINS    (1 << 20)          // (4*8*512*512) >> 3, lambda = 0.5/bin
#define OFF_BITS 4                 // intra-bin arrival offset
#define BPB     256                // bins per k_mega block (~128 positions)
#define NTILES  1024               // scan tiles (1024 bins each)
#define PCAP    512                // max positions per mega block (Poisson(128))
#define EPSV    1e-5f

typedef float f32x4 __attribute__((ext_vector_type(4)));

static __device__ __forceinline__ void nt_store4(float* p, f32x4 v) {
    __builtin_nontemporal_store(v, (f32x4*)p);
}

// Store model v2 (fitted r3-r12): the nt flag is NOT the variable; per-stream
// DRAM contiguity is. rocclr fill = ~850 waves x MB-contiguous runs -> 6.9
// TB/s. Grid-stride (16K waves x 1KB hops @16MB stride) -> 2.6-2.8 TB/s.
// Conditional hole-y -> 1.1 TB/s. Fix: wave-contiguous chunked prefill.
//
// ws ints: hist[BINS] | ticket(1)+pad(3) | tiles[2*NTILES] | cursor[BINS]
//          | packed[N] | recs[2*N]

#define CLR_INTS (BINS + 4 + 2 * NTILES)
#define CLR_4    (CLR_INTS / 4 + 1)
#define OUT0_4   (N_VOX * COUT / 4)            // 16,777,216 float4s in out_f
#define TOT_4    (N_VOX * (COUT + 4) / 4)      // 17,301,504 = 2048 * 8448
#define ZBLOCKS  512
#define PERWAVE  (TOT_4 / (ZBLOCKS * 4))       // 8448 float4s per wave
#define WITERS   (PERWAVE / 64)                // 132 iterations

// prefill: each wave owns one contiguous 528KB chunk, written sequentially.
__global__ __launch_bounds__(256) void k_zero(float* __restrict__ out,
                                              int* __restrict__ ws) {
    int tid = threadIdx.x;
    int lane = tid & 63;
    int wave = (blockIdx.x << 2) | (tid >> 6);          // 0..2047
    size_t base = (size_t)wave * PERWAVE + lane;        // float4 units
    f32x4 z  = {0.f, 0.f, 0.f, 0.f};
    f32x4 mi = {-1.f, -1.f, -1.f, -1.f};
    #pragma unroll 4
    for (int i = 0; i < WITERS; i++) {
        size_t t4 = base + (size_t)i * 64;
        *(f32x4*)&out[t4 * 4] = (t4 < (size_t)OUT0_4) ? z : mi;
    }
    // ws metadata clear: block-contiguous chunks (4.2 MB total, minor)
    int wchunk = (CLR_4 + ZBLOCKS - 1) / ZBLOCKS;       // int4s per block
    int wbase = blockIdx.x * wchunk;
    int wend = wbase + wchunk; if (wend > CLR_4) wend = CLR_4;
    for (int t = wbase + tid; t < wend; t += 256) {
        if (t * 4 < CLR_INTS) *(int4*)&ws[t * 4] = make_int4(0, 0, 0, 0);
    }
}

__global__ void k_hist(const int* __restrict__ idx, unsigned* __restrict__ packed,
                       int* __restrict__ hist) {
    int j = blockIdx.x * 256 + threadIdx.x;
    int4 v = *(const int4*)&idx[j * 4];
    int lin = ((v.x * 8 + v.y) * 512 + v.z) * 512 + v.w;
    int off = atomicAdd(&hist[lin >> BIN_SHIFT], 1);
    packed[j] = ((unsigned)lin << OFF_BITS) | (unsigned)off;
}

// single-kernel exclusive scan, decoupled lookback, ticket-ordered tiles.
__global__ __launch_bounds__(256) void k_scan(
    const int* __restrict__ hist, int* __restrict__ cursor,
    unsigned long long* __restrict__ tiles, int* __restrict__ ticket) {
    __shared__ int stile;
    __shared__ int wsums[4];
    __shared__ int sprefix;
    int tid = threadIdx.x;
    if (tid == 0) stile = atomicAdd(ticket, 1);
    __syncthreads();
    int tile = stile;
    int base = tile * 1024 + tid * 4;
    int4 v = *(const int4*)&hist[base];
    int t3 = v.x + v.y + v.z + v.w;
    int lane = tid & 63, w = tid >> 6;
    int incl = t3;
    #pragma unroll
    for (int off = 1; off < 64; off <<= 1) {
        int u = __shfl_up(incl, off);
        if (lane >= off) incl += u;
    }
    if (lane == 63) wsums[w] = incl;
    __syncthreads();
    int woff = (w > 0 ? wsums[0] : 0) + (w > 1 ? wsums[1] : 0) + (w > 2 ? wsums[2] : 0);
    int total = wsums[0] + wsums[1] + wsums[2] + wsums[3];
    int texcl = woff + incl - t3;
    if (tid == 0) {
        unsigned long long st = (tile == 0) ? 2ull : 1ull;
        atomicExch(&tiles[tile], (st << 40) | (unsigned long long)(unsigned)total);
        int pfx = 0;
        if (tile > 0) {
            int p = tile - 1;
            while (true) {
                unsigned long long d = atomicAdd(&tiles[p], 0ull);
                unsigned long long st2 = d >> 40;
                if (st2 == 0) { __builtin_amdgcn_s_sleep(2); continue; }
                pfx += (int)(unsigned)(d & 0xFFFFFFFFull);
                if (st2 == 2ull) break;
                p--;
            }
            atomicExch(&tiles[tile],
                       (2ull << 40) | (unsigned long long)(unsigned)(pfx + total));
        }
        sprefix = pfx;
    }
    __syncthreads();
    int prefix = sprefix + texcl;
    int4 e;
    e.x = prefix;
    e.y = prefix + v.x;
    e.z = prefix + v.x + v.y;
    e.w = prefix + v.x + v.y + v.z;
    *(int4*)&cursor[base] = e;
}

// writes sorted-position records (lin, origrow): k_mega Phase A is coalesced.
__global__ void k_scatter(const unsigned* __restrict__ packed, const int* __restrict__ cursor,
                          uint2* __restrict__ recs) {
    int j = blockIdx.x * 256 + threadIdx.x;
    unsigned p = packed[j];
    unsigned lin = p >> OFF_BITS;
    int pos = cursor[lin >> BIN_SHIFT] + (int)(p & ((1u << OFF_BITS) - 1u));
    recs[pos] = make_uint2(lin, (unsigned)j);
}

// ---------- fused fixup + GEMM + LN (valid rows only) ----------
__global__ __launch_bounds__(256) void k_mega(
    const float* __restrict__ feats, const float* __restrict__ weight,
    const float* __restrict__ gamma, const float* __restrict__ beta,
    const int* __restrict__ hist, const int* __restrict__ cursor,
    const uint2* __restrict__ recs, float* __restrict__ out) {
    __shared__ float featb[4][8][CIN];         // 8 KB (wave-private slices)
    __shared__ unsigned slin[PCAP];            // 2 KB
    __shared__ int sperm[PCAP];                // 2 KB
    __shared__ unsigned short vpos[PCAP];      // 1 KB
    __shared__ int wsum[4];

    int tid = threadIdx.x;
    int w = tid >> 6, lane = tid & 63;
    int B0 = blockIdx.x * BPB;
    int p0 = cursor[B0];
    int p1 = (B0 + BPB < BINS) ? cursor[B0 + BPB] : N_VOX;
    int npos = p1 - p0;                        // ~Poisson(128), < PCAP

    // Phase A1: coalesced load of records into LDS
    for (int lp = tid; lp < npos; lp += 256) {
        uint2 r = recs[p0 + lp];
        slin[lp] = r.x;
        sperm[lp] = (int)r.y;
    }
    __syncthreads();

    // Phase A2: per-bin stable fixup in LDS (key = lin<<19 | j) + validity
    int b = B0 + tid;
    int c = hist[b];
    int ls = cursor[b] - p0;
    if (c >= 2) {
        for (int i = 1; i < c; i++) {
            unsigned lj = slin[ls + i];
            int pj = sperm[ls + i];
            unsigned long long kj = ((unsigned long long)lj << 19) | (unsigned)pj;
            int m = i - 1;
            while (m >= 0) {
                unsigned lm = slin[ls + m];
                int pm = sperm[ls + m];
                unsigned long long km = ((unsigned long long)lm << 19) | (unsigned)pm;
                if (km <= kj) break;
                slin[ls + m + 1] = lm;
                sperm[ls + m + 1] = pm;
                m--;
            }
            slin[ls + m + 1] = lj;
            sperm[ls + m + 1] = pj;
        }
    }
    int myv = 0;
    for (int i = 0; i < c; i++)
        myv += ((slin[ls + i] & 0x201u) == 0u) ? 1 : 0;
    int incl = myv;
    #pragma unroll
    for (int off = 1; off < 64; off <<= 1) {
        int u = __shfl_up(incl, off);
        if (lane >= off) incl += u;
    }
    if (lane == 63) wsum[w] = incl;
    __syncthreads();
    int s0 = wsum[0], s1 = wsum[1], s2 = wsum[2], s3 = wsum[3];
    int nv = s0 + s1 + s2 + s3;
    int woff = (w > 0 ? s0 : 0) + (w > 1 ? s1 : 0) + (w > 2 ? s2 : 0);
    int basev = woff + incl - myv;
    for (int i = 0; i < c; i++) {
        int lp = ls + i;
        if ((slin[lp] & 0x201u) == 0u) vpos[basev++] = (unsigned short)lp;
    }
    __syncthreads();

    // Phase C: GEMM + LN, 2 rows per wave pass (32-lane halves), f32x4 nt stores
    if (nv == 0) return;
    int half = lane >> 5, l32 = lane & 31;
    const f32x4* Wg4 = (const f32x4*)weight;   // [64][32] of float4
    f32x4 gv = *(const f32x4*)&gamma[l32 * 4];
    f32x4 bv = *(const f32x4*)&beta[l32 * 4];

    for (int m0 = 0; m0 < nv; m0 += 32) {
        int mb = m0 + w * 8;
        if (mb >= nv) continue;                 // no barriers below: safe
        #pragma unroll
        for (int i = 0; i < 8; i++) {
            int m = mb + i;
            int lp = vpos[(m < nv) ? m : 0];
            featb[w][i][lane] = feats[(size_t)sperm[lp] * CIN + lane];
        }

        f32x4 acc[4];
        #pragma unroll
        for (int i = 0; i < 4; i++) acc[i] = (f32x4){0.f, 0.f, 0.f, 0.f};

        #pragma unroll 4
        for (int k0 = 0; k0 < CIN; k0 += 4) {
            f32x4 wv0 = Wg4[(k0 + 0) * 32 + l32];
            f32x4 wv1 = Wg4[(k0 + 1) * 32 + l32];
            f32x4 wv2 = Wg4[(k0 + 2) * 32 + l32];
            f32x4 wv3 = Wg4[(k0 + 3) * 32 + l32];
            #pragma unroll
            for (int ii = 0; ii < 4; ii++) {
                float4 f = *(float4*)&featb[w][2 * ii + half][k0];
                acc[ii] += f.x * wv0;
                acc[ii] += f.y * wv1;
                acc[ii] += f.z * wv2;
                acc[ii] += f.w * wv3;
            }
        }

        #pragma unroll
        for (int ii = 0; ii < 4; ii++) {
            int m = mb + 2 * ii + half;
            f32x4 a = acc[ii];
            float sm = a.x + a.y + a.z + a.w;
            float sq = a.x * a.x + a.y * a.y + a.z * a.z + a.w * a.w;
            #pragma unroll
            for (int off = 16; off > 0; off >>= 1) {   // reduce within 32-lane half
                sm += __shfl_xor(sm, off);
                sq += __shfl_xor(sq, off);
            }
            float mean = sm * (1.0f / COUT);
            float var  = fmaxf(sq * (1.0f / COUT) - mean * mean, 0.0f);
            float rstd = rsqrtf(var + EPSV);
            if (m < nv) {
                int lp = vpos[m];
                int pos = p0 + lp;
                f32x4 o = (a - mean) * rstd * gv + bv;
                nt_store4(&out[(size_t)pos * COUT + l32 * 4], o);
                if (l32 == 0) {
                    unsigned lin = slin[lp];
                    f32x4 ni;
                    ni.x = (float)(lin >> 21);
                    ni.y = (float)((lin >> 18) & 7u);
                    ni.z = (float)(((lin >> 9) & 511u) >> 1);
                    ni.w = (float)((lin & 511u) >> 1);
                    nt_store4(&out[(size_t)N_VOX * COUT + (size_t)pos * 4], ni);
                }
            }
        }
    }
}

extern "C" void kernel_launch(void* const* d_in, const int* in_sizes, int n_in,
                              void* d_out, int out_size, void* d_ws, size_t ws_size,
                              hipStream_t stream) {
    const float* feats  = (const float*)d_in[0];
    const int*   idx    = (const int*)d_in[1];
    const float* weight = (const float*)d_in[2];
    const float* gamma  = (const float*)d_in[3];
    const float* beta   = (const float*)d_in[4];
    float* out = (float*)d_out;

    int* ws = (int*)d_ws;
    int*                hist   = ws;                         // BINS
    int*                ticket = ws + BINS;                  // 1 (+3 pad)
    unsigned long long* tiles  = (unsigned long long*)(ws + BINS + 4);  // NTILES
    int*                cursor = ws + BINS + 4 + 2 * NTILES; // BINS
    unsigned*           packed = (unsigned*)(cursor + BINS); // N
    uint2*              recs   = (uint2*)(packed + N_VOX);   // N x 8B

    k_zero<<<ZBLOCKS, 256, 0, stream>>>(out, ws);
    k_hist<<<N_VOX / 256, 256, 0, stream>>>(idx, packed, hist);
    k_scan<<<NTILES, 256, 0, stream>>>(hist, cursor, tiles, ticket);
    k_scatter<<<N_VOX / 256, 256, 0, stream>>>(packed, cursor, recs);
    k_mega<<<BINS / BPB, 256, 0, stream>>>(feats, weight, gamma, beta,
                                           hist, cursor, recs, out);
}

// Round 14
// 179.438 us; speedup vs baseline: 1.4946x; 1.0159x over previous
//
#include <hip/hip_runtime.h>
#include <stdint.h>

#define N_VOX   (1 << 19)
#define CIN     64
#define COUT    128
#define BIN_SHIFT 3
#define BINS    (1 << 20)          // (4*8*512*512) >> 3, lambda = 0.5/bin
#define OFF_BITS 4                 // intra-bin arrival offset
#define BPB     256                // bins per k_mega block (~128 positions)
#define NTILES  1024               // scan tiles (1024 bins each)
#define PCAP    512                // max positions per mega block (Poisson(128))
#define EPSV    1e-5f

typedef float f32x4 __attribute__((ext_vector_type(4)));

// Round-14 design: single-writer dense output. k_mega stages valid-row LN
// results in LDS (32 rows/sweep) and then writes ALL positions in ascending
// dense order (staged data | zeros; decoded idx | -1). No prefill over d_out,
// no scattered output stores, every output byte written exactly once.
// Total writes 353 -> 276 MB, all fill-pattern dense.
//
// ws ints: hist[BINS] | ticket(1)+pad(3) | tiles[2*NTILES] | cursor[BINS]
//          | packed[N] | recs[2*N]

#define CLR_INTS (BINS + 4 + 2 * NTILES)
#define CLR_4    (CLR_INTS / 4 + 1)

__global__ void k_clear(int* __restrict__ p) {
    int t = blockIdx.x * 256 + threadIdx.x;
    if (t * 4 < CLR_INTS) *(int4*)&p[t * 4] = make_int4(0, 0, 0, 0);
}

__global__ void k_hist(const int* __restrict__ idx, unsigned* __restrict__ packed,
                       int* __restrict__ hist) {
    int j = blockIdx.x * 256 + threadIdx.x;
    int4 v = *(const int4*)&idx[j * 4];
    int lin = ((v.x * 8 + v.y) * 512 + v.z) * 512 + v.w;
    int off = atomicAdd(&hist[lin >> BIN_SHIFT], 1);
    packed[j] = ((unsigned)lin << OFF_BITS) | (unsigned)off;
}

// single-kernel exclusive scan, decoupled lookback, ticket-ordered tiles.
__global__ __launch_bounds__(256) void k_scan(
    const int* __restrict__ hist, int* __restrict__ cursor,
    unsigned long long* __restrict__ tiles, int* __restrict__ ticket) {
    __shared__ int stile;
    __shared__ int wsums[4];
    __shared__ int sprefix;
    int tid = threadIdx.x;
    if (tid == 0) stile = atomicAdd(ticket, 1);
    __syncthreads();
    int tile = stile;
    int base = tile * 1024 + tid * 4;
    int4 v = *(const int4*)&hist[base];
    int t3 = v.x + v.y + v.z + v.w;
    int lane = tid & 63, w = tid >> 6;
    int incl = t3;
    #pragma unroll
    for (int off = 1; off < 64; off <<= 1) {
        int u = __shfl_up(incl, off);
        if (lane >= off) incl += u;
    }
    if (lane == 63) wsums[w] = incl;
    __syncthreads();
    int woff = (w > 0 ? wsums[0] : 0) + (w > 1 ? wsums[1] : 0) + (w > 2 ? wsums[2] : 0);
    int total = wsums[0] + wsums[1] + wsums[2] + wsums[3];
    int texcl = woff + incl - t3;
    if (tid == 0) {
        unsigned long long st = (tile == 0) ? 2ull : 1ull;
        atomicExch(&tiles[tile], (st << 40) | (unsigned long long)(unsigned)total);
        int pfx = 0;
        if (tile > 0) {
            int p = tile - 1;
            while (true) {
                unsigned long long d = atomicAdd(&tiles[p], 0ull);
                unsigned long long st2 = d >> 40;
                if (st2 == 0) { __builtin_amdgcn_s_sleep(2); continue; }
                pfx += (int)(unsigned)(d & 0xFFFFFFFFull);
                if (st2 == 2ull) break;
                p--;
            }
            atomicExch(&tiles[tile],
                       (2ull << 40) | (unsigned long long)(unsigned)(pfx + total));
        }
        sprefix = pfx;
    }
    __syncthreads();
    int prefix = sprefix + texcl;
    int4 e;
    e.x = prefix;
    e.y = prefix + v.x;
    e.z = prefix + v.x + v.y;
    e.w = prefix + v.x + v.y + v.z;
    *(int4*)&cursor[base] = e;
}

// writes sorted-position records (lin, origrow): k_mega Phase A is coalesced.
__global__ void k_scatter(const unsigned* __restrict__ packed, const int* __restrict__ cursor,
                          uint2* __restrict__ recs) {
    int j = blockIdx.x * 256 + threadIdx.x;
    unsigned p = packed[j];
    unsigned lin = p >> OFF_BITS;
    int pos = cursor[lin >> BIN_SHIFT] + (int)(p & ((1u << OFF_BITS) - 1u));
    recs[pos] = make_uint2(lin, (unsigned)j);
}

// ---------- fused fixup + GEMM + LN + dense single-pass output ----------
__global__ __launch_bounds__(256) void k_mega(
    const float* __restrict__ feats, const float* __restrict__ weight,
    const float* __restrict__ gamma, const float* __restrict__ beta,
    const int* __restrict__ hist, const int* __restrict__ cursor,
    const uint2* __restrict__ recs, float* __restrict__ out) {
    __shared__ float featb[4][8][CIN];         // 8 KB (wave-private slices)
    __shared__ float sstage[32][COUT];         // 16 KB staged LN rows
    __shared__ unsigned slin[PCAP];            // 2 KB
    __shared__ int sperm[PCAP];                // 2 KB
    __shared__ unsigned short vpos[PCAP];      // 1 KB (ascending)
    __shared__ unsigned char sslot[PCAP];      // 0.5 KB: m&31 or 0xFF
    __shared__ int wsum[4];

    int tid = threadIdx.x;
    int w = tid >> 6, lane = tid & 63;
    int B0 = blockIdx.x * BPB;
    int p0 = cursor[B0];
    int p1 = (B0 + BPB < BINS) ? cursor[B0 + BPB] : N_VOX;
    int npos = p1 - p0;                        // ~Poisson(128), < PCAP

    // Phase A1: coalesced load of records into LDS
    for (int lp = tid; lp < npos; lp += 256) {
        uint2 r = recs[p0 + lp];
        slin[lp] = r.x;
        sperm[lp] = (int)r.y;
        sslot[lp] = 0xFFu;
    }
    __syncthreads();

    // Phase A2: per-bin stable fixup in LDS (key = lin<<19 | j) + validity
    int b = B0 + tid;
    int c = hist[b];
    int ls = cursor[b] - p0;
    if (c >= 2) {
        for (int i = 1; i < c; i++) {
            unsigned lj = slin[ls + i];
            int pj = sperm[ls + i];
            unsigned long long kj = ((unsigned long long)lj << 19) | (unsigned)pj;
            int m = i - 1;
            while (m >= 0) {
                unsigned lm = slin[ls + m];
                int pm = sperm[ls + m];
                unsigned long long km = ((unsigned long long)lm << 19) | (unsigned)pm;
                if (km <= kj) break;
                slin[ls + m + 1] = lm;
                sperm[ls + m + 1] = pm;
                m--;
            }
            slin[ls + m + 1] = lj;
            sperm[ls + m + 1] = pj;
        }
    }
    int myv = 0;
    for (int i = 0; i < c; i++)
        myv += ((slin[ls + i] & 0x201u) == 0u) ? 1 : 0;
    int incl = myv;
    #pragma unroll
    for (int off = 1; off < 64; off <<= 1) {
        int u = __shfl_up(incl, off);
        if (lane >= off) incl += u;
    }
    if (lane == 63) wsum[w] = incl;
    __syncthreads();
    int s0 = wsum[0], s1 = wsum[1], s2 = wsum[2], s3 = wsum[3];
    int nv = s0 + s1 + s2 + s3;
    int woff = (w > 0 ? s0 : 0) + (w > 1 ? s1 : 0) + (w > 2 ? s2 : 0);
    int basev = woff + incl - myv;
    for (int i = 0; i < c; i++) {
        int lp = ls + i;
        if ((slin[lp] & 0x201u) == 0u) {
            vpos[basev] = (unsigned short)lp;
            sslot[lp] = (unsigned char)(basev & 31);
            basev++;
        }
    }
    __syncthreads();

    int half = lane >> 5, l32 = lane & 31;
    float* oidx = out + (size_t)N_VOX * COUT;
    f32x4 z = {0.f, 0.f, 0.f, 0.f};

    if (nv == 0) {                              // block-uniform, no barriers
        f32x4 mi = {-1.f, -1.f, -1.f, -1.f};
        for (int lp = w * 2 + half; lp < npos; lp += 8)
            *(f32x4*)&out[(size_t)(p0 + lp) * COUT + l32 * 4] = z;
        for (int lp = tid; lp < npos; lp += 256)
            *(f32x4*)&oidx[(size_t)(p0 + lp) * 4] = mi;
        return;
    }

    const f32x4* Wg4 = (const f32x4*)weight;   // [64][32] of float4
    f32x4 gv = *(const f32x4*)&gamma[l32 * 4];
    f32x4 bv = *(const f32x4*)&beta[l32 * 4];
    int wcur = 0;

    for (int m0 = 0; m0 < nv; m0 += 32) {       // uniform sweep loop
        int mb = m0 + w * 8;
        if (mb < nv) {
            #pragma unroll
            for (int i = 0; i < 8; i++) {
                int m = mb + i;
                int lp = vpos[(m < nv) ? m : 0];
                featb[w][i][lane] = feats[(size_t)sperm[lp] * CIN + lane];
            }
            f32x4 acc[4];
            #pragma unroll
            for (int i = 0; i < 4; i++) acc[i] = z;
            #pragma unroll 4
            for (int k0 = 0; k0 < CIN; k0 += 4) {
                f32x4 wv0 = Wg4[(k0 + 0) * 32 + l32];
                f32x4 wv1 = Wg4[(k0 + 1) * 32 + l32];
                f32x4 wv2 = Wg4[(k0 + 2) * 32 + l32];
                f32x4 wv3 = Wg4[(k0 + 3) * 32 + l32];
                #pragma unroll
                for (int ii = 0; ii < 4; ii++) {
                    float4 f = *(float4*)&featb[w][2 * ii + half][k0];
                    acc[ii] += f.x * wv0;
                    acc[ii] += f.y * wv1;
                    acc[ii] += f.z * wv2;
                    acc[ii] += f.w * wv3;
                }
            }
            #pragma unroll
            for (int ii = 0; ii < 4; ii++) {
                int m = mb + 2 * ii + half;
                f32x4 a = acc[ii];
                float sm = a.x + a.y + a.z + a.w;
                float sq = a.x * a.x + a.y * a.y + a.z * a.z + a.w * a.w;
                #pragma unroll
                for (int off = 16; off > 0; off >>= 1) {
                    sm += __shfl_xor(sm, off);
                    sq += __shfl_xor(sq, off);
                }
                float mean = sm * (1.0f / COUT);
                float var  = fmaxf(sq * (1.0f / COUT) - mean * mean, 0.0f);
                float rstd = rsqrtf(var + EPSV);
                if (m < nv) {
                    f32x4 o = (a - mean) * rstd * gv + bv;
                    *(f32x4*)&sstage[m & 31][l32 * 4] = o;
                }
            }
        }
        __syncthreads();                        // staging visible to all

        int end = (m0 + 32 < nv) ? vpos[m0 + 32] : npos;
        // dense feature rows [wcur, end): 8 rows/iter, ascending
        for (int lp = wcur + w * 2 + half; lp < end; lp += 8) {
            int sl = sslot[lp];
            f32x4 o = (sl != 0xFF) ? *(f32x4*)&sstage[sl][l32 * 4] : z;
            *(f32x4*)&out[(size_t)(p0 + lp) * COUT + l32 * 4] = o;
        }
        // dense new_idx rows [wcur, end)
        for (int lp = wcur + tid; lp < end; lp += 256) {
            f32x4 ni;
            if (sslot[lp] != 0xFF) {
                unsigned lin = slin[lp];
                ni.x = (float)(lin >> 21);
                ni.y = (float)((lin >> 18) & 7u);
                ni.z = (float)(((lin >> 9) & 511u) >> 1);
                ni.w = (float)((lin & 511u) >> 1);
            } else {
                ni = (f32x4){-1.f, -1.f, -1.f, -1.f};
            }
            *(f32x4*)&oidx[(size_t)(p0 + lp) * 4] = ni;
        }
        wcur = end;
        __syncthreads();                        // before next sweep reuses sstage
    }
}

extern "C" void kernel_launch(void* const* d_in, const int* in_sizes, int n_in,
                              void* d_out, int out_size, void* d_ws, size_t ws_size,
                              hipStream_t stream) {
    const float* feats  = (const float*)d_in[0];
    const int*   idx    = (const int*)d_in[1];
    const float* weight = (const float*)d_in[2];
    const float* gamma  = (const float*)d_in[3];
    const float* beta   = (const float*)d_in[4];
    float* out = (float*)d_out;

    int* ws = (int*)d_ws;
    int*                hist   = ws;                         // BINS
    int*                ticket = ws + BINS;                  // 1 (+3 pad)
    unsigned long long* tiles  = (unsigned long long*)(ws + BINS + 4);  // NTILES
    int*                cursor = ws + BINS + 4 + 2 * NTILES; // BINS
    unsigned*           packed = (unsigned*)(cursor + BINS); // N
    uint2*              recs   = (uint2*)(packed + N_VOX);   // N x 8B

    k_clear<<<(CLR_4 + 255) / 256, 256, 0, stream>>>(ws);
    k_hist<<<N_VOX / 256, 256, 0, stream>>>(idx, packed, hist);
    k_scan<<<NTILES, 256, 0, stream>>>(hist, cursor, tiles, ticket);
    k_scatter<<<N_VOX / 256, 256, 0, stream>>>(packed, cursor, recs);
    k_mega<<<BINS / BPB, 256, 0, stream>>>(feats, weight, gamma, beta,
                                           hist, cursor, recs, out);
}